// Round 3
// baseline (89.502 us; speedup 1.0000x reference)
//
#include <hip/hip_runtime.h>

// Problem constants (fixed by setup_inputs): B=8, N=128, C=64, S=64, basis=20
constexpr int B = 8, N = 128, C = 64, S = 64;
constexpr float INV_AVG = 1.0f / 49.0f;   // AVG_NOBJ
constexpr float SLOPE = 0.01f;            // leaky_relu neg slope

// Native 4-float vector for nontemporal builtins (HIP float4 is a class type
// that __builtin_nontemporal_store rejects).
typedef float f4 __attribute__((ext_vector_type(4)));

// Workspace layout (float offsets)
constexpr int WS_A  = 0;                 // [B][N][S]  diag-x term   (65536)
constexpr int WS_R  = 65536;             // [B][N][S]  row (x_j) term
constexpr int WS_C  = 131072;            // [B][N][S]  col (x_i) term
constexpr int WS_D  = 196608;            // [B][S]     diag agg term (512)
constexpr int WS_E  = 197120;            // [B][S]     everywhere agg term
constexpr int WS_W1 = 197632;            // [C][S] aggregation-summed weights
constexpr int WS_W2 = 201728;            // [C][S]
constexpr int WS_W3 = 205824;            // [C][S]   (end: 209920 floats ~840KB)

// ---------------------------------------------------------------------------
// Kernel 1 (grid 24): build reduced weights ONCE + aggregations.
//   blocks 0..15 : W1/W2/W3[d][s] = sum over 4 aggregation blocks of
//                  coefs[d][s][5a+k], k=0,1,2. One (d,s) per thread,
//                  5 aligned float4 loads cover the whole 20-float row.
//   blocks 16..23: per-n sum/max/min over i, then D,E (small GEMV).
// ---------------------------------------------------------------------------
__global__ __launch_bounds__(256) void weights_agg_kernel(
    const float* __restrict__ x,      // [B][N][C]
    const float* __restrict__ nobj,   // [B]
    const float* __restrict__ coefs,  // [C][S][20]
    float* __restrict__ ws)
{
  const int tid = threadIdx.x;
  if (blockIdx.x < 16) {
    const int e = blockIdx.x * 256 + tid;      // e = d*64 + s, in [0,4096)
    const float4* cp = (const float4*)(coefs + e * 20);  // 80B-aligned ✓
    float4 f0 = cp[0], f1 = cp[1], f2 = cp[2], f3 = cp[3], f4v = cp[4];
    ws[WS_W1 + e] = f0.x + f1.y + f2.z + f3.w;   // b = 0,5,10,15
    ws[WS_W2 + e] = f0.y + f1.z + f2.w + f4v.x;  // b = 1,6,11,16
    ws[WS_W3 + e] = f0.z + f1.w + f3.x + f4v.y;  // b = 2,7,12,17
  } else {
    __shared__ float smem[9216];
    const int n = blockIdx.x - 16;
    float* xs  = smem;          // [N][C] 8192
    float* ps  = smem + 8192;   // [4][64] partial sums
    __shared__ float pmx[256], pmn[256], ag[256];

    const float4* xg = (const float4*)(x + n * N * C);
    float4* xs4 = (float4*)xs;
#pragma unroll
    for (int k = 0; k < 8; ++k) xs4[tid + k * 256] = xg[tid + k * 256];
    __syncthreads();

    const int d = tid & 63, grp = tid >> 6;
    float sm = 0.f, mx = -INFINITY, mn = INFINITY;
    for (int i = grp * 32; i < grp * 32 + 32; ++i) {
      float v = xs[i * 64 + d];
      sm += v;
      mx = fmaxf(mx, v);
      mn = fminf(mn, v);
    }
    ps [grp * 64 + d] = sm;
    pmx[grp * 64 + d] = mx;
    pmn[grp * 64 + d] = mn;
    __syncthreads();

    if (tid < 64) {
      float s0 = ps[tid] + ps[64 + tid] + ps[128 + tid] + ps[192 + tid];
      float m0 = fmaxf(fmaxf(pmx[tid], pmx[64 + tid]),
                       fmaxf(pmx[128 + tid], pmx[192 + tid]));
      float n0 = fminf(fminf(pmn[tid], pmn[64 + tid]),
                       fminf(pmn[128 + tid], pmn[192 + tid]));
      ag[tid]       = s0 * INV_AVG;      // 'sum'
      ag[64 + tid]  = s0 / nobj[n];      // 'mean'
      ag[128 + tid] = m0;                // 'max'
      ag[192 + tid] = n0;                // 'min'
    }
    __syncthreads();

    if (tid < 64) {
      const int s = tid;
      float dv = 0.f, ev = 0.f;
      for (int d2 = 0; d2 < 64; ++d2) {
        const float* cp = coefs + d2 * (S * 20) + s * 20;
        float a0 = ag[d2], a1 = ag[64 + d2], a2 = ag[128 + d2], a3 = ag[192 + d2];
        dv += a0 * cp[3] + a1 * cp[8] + a2 * cp[13] + a3 * cp[18];
        ev += a0 * cp[4] + a1 * cp[9] + a2 * cp[14] + a3 * cp[19];
      }
      ws[WS_D + n * S + s] = dv;
      ws[WS_E + n * S + s] = ev;
    }
  }
}

// ---------------------------------------------------------------------------
// Kernel 2 (grid 64): A/R/Cc GEMM. Block = (n, 16 i-rows). W read coalesced
// straight from global (L2-hot, 256B/wave/load); x rows via LDS broadcast.
// ---------------------------------------------------------------------------
__global__ __launch_bounds__(256) void gemm_kernel(
    const float* __restrict__ x,
    const float* __restrict__ ws_r,   // read view
    float* __restrict__ ws)
{
  __shared__ float xs[16 * 64];
  const int n  = blockIdx.x >> 3;
  const int i0 = (blockIdx.x & 7) << 4;
  const int tid = threadIdx.x;

  // 16 rows x 64 = 1024 floats = 256 float4, coalesced
  ((float4*)xs)[tid] = ((const float4*)(x + (n * N + i0) * C))[tid];
  __syncthreads();

  const int s = tid & 63;
  const int g = tid >> 6;              // wave id: rows g*4 .. g*4+3
  const float* W1 = ws_r + WS_W1;
  const float* W2 = ws_r + WS_W2;
  const float* W3 = ws_r + WS_W3;

  float a1[4] = {0,0,0,0}, a2[4] = {0,0,0,0}, a3[4] = {0,0,0,0};
#pragma unroll 8
  for (int d = 0; d < 64; ++d) {
    float w1 = W1[d * 64 + s];         // coalesced across lanes
    float w2 = W2[d * 64 + s];
    float w3 = W3[d * 64 + s];
#pragma unroll
    for (int k = 0; k < 4; ++k) {
      float xv = xs[(g * 4 + k) * 64 + d];   // wave-uniform broadcast
      a1[k] += xv * w1;
      a2[k] += xv * w2;
      a3[k] += xv * w3;
    }
  }
#pragma unroll
  for (int k = 0; k < 4; ++k) {
    const int o = (n * N + i0 + g * 4 + k) * S + s;   // coalesced per k
    ws[WS_A + o] = a1[k];
    ws[WS_R + o] = a2[k];
    ws[WS_C + o] = a3[k];
  }
}

// ---------------------------------------------------------------------------
// Kernel 3 (grid 1024): assembly. Block = (n,i). The j-invariant part
// (Cc+E+bias) is loaded once per thread and reused over 8 j-iterations.
// Wave stores 1KB contiguous; nontemporal to spare L2.
// ---------------------------------------------------------------------------
__global__ __launch_bounds__(256) void assemble_kernel(
    const float* __restrict__ ws,
    const float* __restrict__ mask,   // [B][N][N][1]
    const float* __restrict__ bias,   // [S]
    float* __restrict__ out)          // [B][N][N][S]
{
  const int bi = blockIdx.x;          // n*128 + i
  const int n  = bi >> 7;
  const int i  = bi & 127;
  const int l  = threadIdx.x & 15;    // float4 slot in S row
  const int jg = threadIdx.x >> 4;    // 0..15

  const float4* A4 = (const float4*)(ws + WS_A);
  const float4* R4 = (const float4*)(ws + WS_R);
  const float4* C4 = (const float4*)(ws + WS_C);
  const float4* D4 = (const float4*)(ws + WS_D);
  const float4* E4 = (const float4*)(ws + WS_E);

  float4 cc = C4[bi * 16 + l];
  float4 ee = E4[n * 16 + l];
  float4 bb = ((const float4*)bias)[l];
  float bx = cc.x + ee.x + bb.x;
  float by = cc.y + ee.y + bb.y;
  float bz = cc.z + ee.z + bb.z;
  float bw = cc.w + ee.w + bb.w;

  f4* out4 = (f4*)out + (size_t)bi * (N * 16);

#pragma unroll
  for (int t = 0; t < 8; ++t) {
    const int j = jg + t * 16;
    float4 rr = R4[(n * N + j) * 16 + l];
    float  m  = mask[bi * N + j];
    float v0 = bx + rr.x;
    float v1 = by + rr.y;
    float v2 = bz + rr.z;
    float v3 = bw + rr.w;
    if (j == i) {
      float4 aa = A4[bi * 16 + l];
      float4 dd = D4[n * 16 + l];
      v0 += aa.x + dd.x; v1 += aa.y + dd.y;
      v2 += aa.z + dd.z; v3 += aa.w + dd.w;
    }
    v0 = (v0 >= 0.f) ? v0 : SLOPE * v0;
    v1 = (v1 >= 0.f) ? v1 : SLOPE * v1;
    v2 = (v2 >= 0.f) ? v2 : SLOPE * v2;
    v3 = (v3 >= 0.f) ? v3 : SLOPE * v3;
    f4 o;
    o.x = v0 * m; o.y = v1 * m; o.z = v2 * m; o.w = v3 * m;
    __builtin_nontemporal_store(o, &out4[j * 16 + l]);
  }
}

extern "C" void kernel_launch(void* const* d_in, const int* in_sizes, int n_in,
                              void* d_out, int out_size, void* d_ws, size_t ws_size,
                              hipStream_t stream) {
  const float* x     = (const float*)d_in[0];   // [8][128][64]
  const float* mask  = (const float*)d_in[1];   // [8][128][128][1]
  const float* nobj  = (const float*)d_in[2];   // [8]
  const float* coefs = (const float*)d_in[3];   // [64][64][20]
  const float* bias  = (const float*)d_in[4];   // [64]
  float* out = (float*)d_out;                   // [8][128][128][64]
  float* ws  = (float*)d_ws;                    // 209920 floats (~840 KB)

  weights_agg_kernel<<<24, 256, 0, stream>>>(x, nobj, coefs, ws);
  gemm_kernel<<<64, 256, 0, stream>>>(x, ws, ws);
  assemble_kernel<<<1024, 256, 0, stream>>>(ws, mask, bias, out);
}

// Round 4
// 83.134 us; speedup vs baseline: 1.0766x; 1.0766x over previous
//
#include <hip/hip_runtime.h>

// Problem constants (fixed by setup_inputs): B=8, N=128, C=64, S=64, basis=20
constexpr int B = 8, N = 128, C = 64, S = 64;
constexpr float INV_AVG = 1.0f / 49.0f;   // AVG_NOBJ
constexpr float SLOPE = 0.01f;            // leaky_relu neg slope

// Native 4-float vector for nontemporal builtins (HIP float4 is a class type
// that __builtin_nontemporal_store rejects).
typedef float f4 __attribute__((ext_vector_type(4)));

// Workspace layout (float offsets)
constexpr int WS_A  = 0;                 // [B][N][S]  diag-x term   (65536)
constexpr int WS_R  = 65536;             // [B][N][S]  row (x_j) term
constexpr int WS_C  = 131072;            // [B][N][S]  col (x_i) term
constexpr int WS_D  = 196608;            // [B][S]     diag agg term (512)
constexpr int WS_E  = 197120;            // [B][S]     everywhere agg term
                                         // end: 197632 floats (~790 KB)

// ---------------------------------------------------------------------------
// Kernel 1 (grid 72): fully independent blocks, no cross-kernel W dependency.
//   blocks 0..63 : GEMM. Each block = (n, 16 i-rows). Builds its own
//                  aggregation-summed W1/W2/W3 in LDS (48 KB) from coefs,
//                  then A/R/Cc = x rows · W{1,3,2}.
//   blocks 64..71: per-n aggregations (sum/max/min over i) -> D,E.
// ---------------------------------------------------------------------------
__global__ __launch_bounds__(256) void prep_kernel(
    const float* __restrict__ x,      // [B][N][C]
    const float* __restrict__ nobj,   // [B]
    const float* __restrict__ coefs,  // [C][S][20]
    float* __restrict__ ws)
{
  __shared__ float smem[13312];       // 53.2 KB, aliased per branch
  const int tid = threadIdx.x;

  if (blockIdx.x < 64) {
    // ---- GEMM branch ----
    float* W1 = smem;                 // [64][64] d-major (e = d*64+s)
    float* W2 = smem + 4096;
    float* W3 = smem + 8192;
    float* xs = smem + 12288;         // 16 rows x 64
    const int n  = blockIdx.x >> 3;
    const int i0 = (blockIdx.x & 7) << 4;

    // Build W: op1/op2/op3 coefs are aggregation-independent -> sum the 4
    // aggregation blocks (b = 5a+k). 16 rows per thread, 5 float4/row.
#pragma unroll
    for (int k = 0; k < 16; ++k) {
      const int e = k * 256 + tid;    // e = d*64 + s
      const float4* cp = (const float4*)(coefs + e * 20);  // 80B-aligned
      float4 f0 = cp[0], f1 = cp[1], f2 = cp[2], f3 = cp[3], f4v = cp[4];
      W1[e] = f0.x + f1.y + f2.z + f3.w;    // b = 0,5,10,15
      W2[e] = f0.y + f1.z + f2.w + f4v.x;   // b = 1,6,11,16
      W3[e] = f0.z + f1.w + f3.x + f4v.y;   // b = 2,7,12,17
    }
    // 16 x-rows = 1024 floats = 256 float4, coalesced
    ((float4*)xs)[tid] = ((const float4*)(x + (n * N + i0) * C))[tid];
    __syncthreads();

    const int s = tid & 63;
    const int g = tid >> 6;           // wave id: rows g*4 .. g*4+3
    float a1[4] = {0,0,0,0}, a2[4] = {0,0,0,0}, a3[4] = {0,0,0,0};
#pragma unroll 8
    for (int d = 0; d < 64; ++d) {
      float w1 = W1[d * 64 + s];      // stride-1 lanes: 2-way bank (free)
      float w2 = W2[d * 64 + s];
      float w3 = W3[d * 64 + s];
#pragma unroll
      for (int k = 0; k < 4; ++k) {
        float xv = xs[(g * 4 + k) * 64 + d];   // wave-uniform broadcast
        a1[k] += xv * w1;
        a2[k] += xv * w2;
        a3[k] += xv * w3;
      }
    }
#pragma unroll
    for (int k = 0; k < 4; ++k) {
      const int o = (n * N + i0 + g * 4 + k) * S + s;   // coalesced per k
      ws[WS_A + o] = a1[k];
      ws[WS_R + o] = a2[k];
      ws[WS_C + o] = a3[k];
    }
  } else {
    // ---- aggregation branch ----
    const int n = blockIdx.x - 64;
    float* xs  = smem;                // [N][C] 8192
    float* ps  = smem + 8192;         // [4][64] partial sums
    float* pmx = smem + 8448;         // [4][64] partial max
    float* pmn = smem + 8704;         // [4][64] partial min
    float* ag  = smem + 8960;         // [4][64] {sum/49, sum/nobj, max, min}

    const float4* xg = (const float4*)(x + n * N * C);
    float4* xs4 = (float4*)xs;
#pragma unroll
    for (int k = 0; k < 8; ++k) xs4[tid + k * 256] = xg[tid + k * 256];
    __syncthreads();

    const int d = tid & 63, grp = tid >> 6;
    float sm = 0.f, mx = -INFINITY, mn = INFINITY;
    for (int i = grp * 32; i < grp * 32 + 32; ++i) {
      float v = xs[i * 64 + d];
      sm += v;
      mx = fmaxf(mx, v);
      mn = fminf(mn, v);
    }
    ps [grp * 64 + d] = sm;
    pmx[grp * 64 + d] = mx;
    pmn[grp * 64 + d] = mn;
    __syncthreads();

    if (tid < 64) {
      float s0 = ps[tid] + ps[64 + tid] + ps[128 + tid] + ps[192 + tid];
      float m0 = fmaxf(fmaxf(pmx[tid], pmx[64 + tid]),
                       fmaxf(pmx[128 + tid], pmx[192 + tid]));
      float n0 = fminf(fminf(pmn[tid], pmn[64 + tid]),
                       fminf(pmn[128 + tid], pmn[192 + tid]));
      ag[tid]       = s0 * INV_AVG;      // 'sum'
      ag[64 + tid]  = s0 / nobj[n];      // 'mean'
      ag[128 + tid] = m0;                // 'max'
      ag[192 + tid] = n0;                // 'min'
    }
    __syncthreads();

    if (tid < 64) {
      const int s = tid;
      float dv = 0.f, ev = 0.f;
      for (int d2 = 0; d2 < 64; ++d2) {
        const float* cp = coefs + d2 * (S * 20) + s * 20;
        float a0 = ag[d2], a1 = ag[64 + d2], a2 = ag[128 + d2], a3 = ag[192 + d2];
        dv += a0 * cp[3] + a1 * cp[8] + a2 * cp[13] + a3 * cp[18];
        ev += a0 * cp[4] + a1 * cp[9] + a2 * cp[14] + a3 * cp[19];
      }
      ws[WS_D + n * S + s] = dv;
      ws[WS_E + n * S + s] = ev;
    }
  }
}

// ---------------------------------------------------------------------------
// Kernel 2 (grid 1024): assembly. Block = (n,i). The j-invariant part
// (Cc+E+bias) is loaded once per thread and reused over 8 j-iterations.
// Wave stores 1KB contiguous; nontemporal to spare L2.
// ---------------------------------------------------------------------------
__global__ __launch_bounds__(256) void assemble_kernel(
    const float* __restrict__ ws,
    const float* __restrict__ mask,   // [B][N][N][1]
    const float* __restrict__ bias,   // [S]
    float* __restrict__ out)          // [B][N][N][S]
{
  const int bi = blockIdx.x;          // n*128 + i
  const int n  = bi >> 7;
  const int i  = bi & 127;
  const int l  = threadIdx.x & 15;    // float4 slot in S row
  const int jg = threadIdx.x >> 4;    // 0..15

  const float4* A4 = (const float4*)(ws + WS_A);
  const float4* R4 = (const float4*)(ws + WS_R);
  const float4* C4 = (const float4*)(ws + WS_C);
  const float4* D4 = (const float4*)(ws + WS_D);
  const float4* E4 = (const float4*)(ws + WS_E);

  float4 cc = C4[bi * 16 + l];
  float4 ee = E4[n * 16 + l];
  float4 bb = ((const float4*)bias)[l];
  float bx = cc.x + ee.x + bb.x;
  float by = cc.y + ee.y + bb.y;
  float bz = cc.z + ee.z + bb.z;
  float bw = cc.w + ee.w + bb.w;

  f4* out4 = (f4*)out + (size_t)bi * (N * 16);

#pragma unroll
  for (int t = 0; t < 8; ++t) {
    const int j = jg + t * 16;
    float4 rr = R4[(n * N + j) * 16 + l];
    float  m  = mask[bi * N + j];
    float v0 = bx + rr.x;
    float v1 = by + rr.y;
    float v2 = bz + rr.z;
    float v3 = bw + rr.w;
    if (j == i) {
      float4 aa = A4[bi * 16 + l];
      float4 dd = D4[n * 16 + l];
      v0 += aa.x + dd.x; v1 += aa.y + dd.y;
      v2 += aa.z + dd.z; v3 += aa.w + dd.w;
    }
    v0 = (v0 >= 0.f) ? v0 : SLOPE * v0;
    v1 = (v1 >= 0.f) ? v1 : SLOPE * v1;
    v2 = (v2 >= 0.f) ? v2 : SLOPE * v2;
    v3 = (v3 >= 0.f) ? v3 : SLOPE * v3;
    f4 o;
    o.x = v0 * m; o.y = v1 * m; o.z = v2 * m; o.w = v3 * m;
    __builtin_nontemporal_store(o, &out4[j * 16 + l]);
  }
}

extern "C" void kernel_launch(void* const* d_in, const int* in_sizes, int n_in,
                              void* d_out, int out_size, void* d_ws, size_t ws_size,
                              hipStream_t stream) {
  const float* x     = (const float*)d_in[0];   // [8][128][64]
  const float* mask  = (const float*)d_in[1];   // [8][128][128][1]
  const float* nobj  = (const float*)d_in[2];   // [8]
  const float* coefs = (const float*)d_in[3];   // [64][64][20]
  const float* bias  = (const float*)d_in[4];   // [64]
  float* out = (float*)d_out;                   // [8][128][128][64]
  float* ws  = (float*)d_ws;                    // 197632 floats (~790 KB)

  prep_kernel<<<72, 256, 0, stream>>>(x, nobj, coefs, ws);
  assemble_kernel<<<1024, 256, 0, stream>>>(ws, mask, bias, out);
}